// Round 2
// baseline (362.621 us; speedup 1.0000x reference)
//
#include <hip/hip_runtime.h>
#include <stdint.h>

// FluteLinear: out[m,n] = sum_k x[m,k] * tables[qweight[n,k]] * scales[n, k/128]
// M=16, N=14336, K=4096, GROUP=128 (G=32). qweight = 235 MB int32 (8x inflated:
// 4-bit codes stored as int32).
//
// Round-4 theory: round-3's gload_lds burst staging was a NULL (328 vs 318 =
// fill drift) -> the q-stream access pattern was never the limiter; the fused
// stream+dequant structure is (bursty vmcnt(0) drains convolved with an
// LDS-heavy consumer). Decouple: qpack compresses 235 MB -> 29.4 MB of nibbles
// (pure contiguous copy shape, runs at copy rate ~6 TB/s, ~45 us); flute_main
// then reads only 29 MB (L2/L3-hot, just written) and is LDS/VALU-bound
// (~20-30 us). One packed uint32 = 8 codes = one MFMA k-slot; pair lookup =
// one byte extract. ws poison each iteration forces re-pack - that's the
// design (pack IS the streaming pass).
//
// Predicted: total 328 -> ~240 +/- 15. If ~290+: pack under copy rate or main
// LDS-bound -> instrument by launch-duplication differencing next round. If
// unchanged: fixed harness cost model wrong -> re-derive budget before editing.

#define K_DIM     4096
#define N_OUT     14336
#define G_CNT     32
#define NSL       8                   // 8 k-slices of 512
#define OUT_ELEMS (16 * 14336)
#define QP_WORDS  ((size_t)N_OUT * (K_DIM / 8))   // 7,340,032 words = 29.36 MB
#define PART_OFF  QP_WORDS                        // float-index of partials in ws

typedef _Float16 f16x8 __attribute__((ext_vector_type(8)));
typedef float    f32x4 __attribute__((ext_vector_type(4)));

union H2U { uint16_t u; _Float16 h; };
union B16 { uint32_t u[4]; f16x8 v; };

typedef const __attribute__((address_space(1))) uint32_t glb_u32;
typedef __attribute__((address_space(3)))       uint32_t lds_u32;

// ---- pack: 32 int32 codes -> 16 B of nibbles (LSB-first). Pure stream. ----
// 1,835,008 threads = 7168 blocks; per wave 8 KB contiguous read, 1 KB write.
__global__ __launch_bounds__(256)
void qpack(const int4* __restrict__ q, uint4* __restrict__ qp) {
    const size_t i = (size_t)blockIdx.x * 256 + threadIdx.x;
    const int4* s = q + i * 8;
    uint32_t w[4];
    #pragma unroll
    for (int g = 0; g < 4; ++g) {
        const int4 a = s[g * 2], b = s[g * 2 + 1];
        w[g] = (uint32_t)(a.x & 15)        | ((uint32_t)(a.y & 15) << 4)
             | ((uint32_t)(a.z & 15) << 8) | ((uint32_t)(a.w & 15) << 12)
             | ((uint32_t)(b.x & 15) << 16)| ((uint32_t)(b.y & 15) << 20)
             | ((uint32_t)(b.z & 15) << 24)| ((uint32_t)(b.w & 15) << 28);
    }
    uint4 o; o.x = w[0]; o.y = w[1]; o.z = w[2]; o.w = w[3];
    qp[i] = o;
}

// ---- main: dequant + MFMA on packed codes (29.4 MB, L2/L3-hot) ----
// 7168 wave-tasks = 1792 blocks x 4 waves; task = 16 n-rows x 512 k.
// Packed q staged to LDS via 4x gload_lds 1KB with word-XOR swizzle
// (w ^= (row&7)<<2) pre-applied on the GLOBAL source (dest must stay linear,
// m104/m173); reads are then <=2-way bank conflicts (free).
__global__ __launch_bounds__(256, 4)
void flute_main(const float*    __restrict__ x,
                const uint32_t* __restrict__ qp,
                const float*    __restrict__ scales,
                const float*    __restrict__ tables,
                float*          __restrict__ part) {
    __shared__ uint32_t stage[4][1024];   // 4 waves x 4 KB: 16 rows x 64 words
    __shared__ uint32_t tabr[1024];       // pair-table, 4-way bank-replicated

    const int tid = threadIdx.x;
    {
        H2U lo, hi;
        lo.h = (_Float16)tables[tid & 15];
        hi.h = (_Float16)tables[tid >> 4];
        const uint32_t v = (uint32_t)lo.u | ((uint32_t)hi.u << 16);
        uint4 q4; q4.x = v; q4.y = v; q4.z = v; q4.w = v;
        *(uint4*)(tabr + tid * 4) = q4;
    }
    __syncthreads();

    const int lane = tid & 63;
    const int wave = tid >> 6;
    const int t    = blockIdx.x * 4 + wave;     // 7168 tasks
    const int kc   = t & 7;                     // 512-k chunk (4 scale groups)
    const int nt   = t >> 3;                    // 0..895
    const int n0   = nt << 4;

    const int col  = lane & 15;                 // n-row (B) / m (A) / n-off (D)
    const int quad = lane >> 4;                 // k-slot
    const int lr   = lane & 3;
    const int swz  = (col & 7) << 2;            // read-side word-XOR

    // ---- stage packed q: 4 x 1 KB contiguous, source pre-swizzled ----
    // LDS word (r, w) holds G(r, w ^ ((r&7)<<2)); instr j covers rows j*4..+3.
    char* stW = (char*)&stage[wave][0];
    #pragma unroll
    for (int j = 0; j < 4; ++j) {
        const int r = j * 4 + (lane >> 4);
        const size_t src = ((size_t)(n0 + r) << 11) + ((size_t)kc << 8)
                         + (size_t)((((lane & 15) ^ (r & 7)) << 4));
        __builtin_amdgcn_global_load_lds((glb_u32*)((const char*)qp + src),
                                         (lds_u32*)(stW + (j << 10)),
                                         16, 0, 0);
    }

    // ---- preload A fragments (f32 x -> f16), overlaps the gload drain ----
    f16x8 a[16];
    {
        const float* xp = x + (size_t)col * K_DIM + kc * 512 + quad * 8;
        #pragma unroll
        for (int s = 0; s < 16; ++s) {
            const float4 lo = *(const float4*)(xp + s * 32);
            const float4 hi = *(const float4*)(xp + s * 32 + 4);
            f16x8 af;
            af[0] = (_Float16)lo.x; af[1] = (_Float16)lo.y;
            af[2] = (_Float16)lo.z; af[3] = (_Float16)lo.w;
            af[4] = (_Float16)hi.x; af[5] = (_Float16)hi.y;
            af[6] = (_Float16)hi.z; af[7] = (_Float16)hi.w;
            a[s] = af;
        }
    }
    const int    n  = n0 + col;
    const float4 sc = *(const float4*)(scales + (size_t)n * G_CNT + kc * 4);

    // staged data + x loads all landed
    asm volatile("s_waitcnt vmcnt(0)" ::: "memory");

    const uint32_t* stR = &stage[wave][0] + col * 64;

    f32x4 acc = {0.f, 0.f, 0.f, 0.f};
    #pragma unroll
    for (int g = 0; g < 4; ++g) {               // one 128-k scale group each
        f32x4 tacc = {0.f, 0.f, 0.f, 0.f};
        #pragma unroll
        for (int sp = 0; sp < 4; ++sp) {
            const int s  = g * 4 + sp;
            const int wq = quad + 4 * s;
            const uint32_t qword = stR[wq ^ swz];   // 8 codes, LSB-first
            B16 bf;
            bf.u[0] = tabr[(((qword      ) & 255) << 2) | lr];
            bf.u[1] = tabr[(((qword >>  8) & 255) << 2) | lr];
            bf.u[2] = tabr[(((qword >> 16) & 255) << 2) | lr];
            bf.u[3] = tabr[(( qword >> 24        ) << 2) | lr];
            tacc = __builtin_amdgcn_mfma_f32_16x16x32_f16(a[s], bf.v, tacc, 0, 0, 0);
        }
        const float scg = g == 0 ? sc.x : g == 1 ? sc.y : g == 2 ? sc.z : sc.w;
        acc[0] += scg * tacc[0]; acc[1] += scg * tacc[1];
        acc[2] += scg * tacc[2]; acc[3] += scg * tacc[3];
    }

    // D layout: col = lane&15 (= n-n0), row = quad*4 + r (= m)
    float* op = part + (size_t)kc * OUT_ELEMS + n;
    #pragma unroll
    for (int r = 0; r < 4; ++r)
        op[(size_t)(quad * 4 + r) * N_OUT] = acc[r];
}

__global__ __launch_bounds__(256)
void flute_reduce(const float4* __restrict__ part, float4* __restrict__ out) {
    const int i = blockIdx.x * 256 + threadIdx.x;   // 0..57343
    float4 s = part[i];
    #pragma unroll
    for (int kc = 1; kc < NSL; ++kc) {
        const float4 u = part[(size_t)kc * (OUT_ELEMS / 4) + i];
        s.x += u.x; s.y += u.y; s.z += u.z; s.w += u.w;
    }
    out[i] = s;
}

// ---- fallback (ws too small): direct unpacked-q path, atomics into out ----
__global__ __launch_bounds__(256, 3)
void flute_atomic(const float* __restrict__ x,
                  const int*   __restrict__ qw,
                  const float* __restrict__ scales,
                  const float* __restrict__ tables,
                  float*       __restrict__ out) {
    __shared__ uint32_t tab2[256];
    {
        H2U lo, hi;
        lo.h = (_Float16)tables[threadIdx.x & 15];
        hi.h = (_Float16)tables[threadIdx.x >> 4];
        tab2[threadIdx.x] = (uint32_t)lo.u | ((uint32_t)hi.u << 16);
    }
    __syncthreads();

    const int lane = threadIdx.x & 63;
    const int wave = threadIdx.x >> 6;
    const int t    = blockIdx.x * 4 + wave;
    const int kc   = t & 7;
    const int nt   = t >> 3;
    const int n0   = nt << 4;
    const int col  = lane & 15;
    const int quad = lane >> 4;
    const int n    = n0 + col;

    const int*   qpp = qw + (size_t)n * K_DIM + kc * 512 + quad * 8;
    const float* xp  = x + (size_t)col * K_DIM + kc * 512 + quad * 8;
    const float4 sc  = *(const float4*)(scales + (size_t)n * G_CNT + kc * 4);

    f32x4 acc = {0.f, 0.f, 0.f, 0.f};
    #pragma unroll
    for (int g = 0; g < 4; ++g) {
        f32x4 tacc = {0.f, 0.f, 0.f, 0.f};
        #pragma unroll
        for (int sp = 0; sp < 4; ++sp) {
            const int s = g * 4 + sp;
            const int4 qa = *(const int4*)(qpp + s * 32);
            const int4 qc = *(const int4*)(qpp + s * 32 + 4);
            const float4 lo = *(const float4*)(xp + s * 32);
            const float4 hi = *(const float4*)(xp + s * 32 + 4);
            f16x8 af;
            af[0] = (_Float16)lo.x; af[1] = (_Float16)lo.y;
            af[2] = (_Float16)lo.z; af[3] = (_Float16)lo.w;
            af[4] = (_Float16)hi.x; af[5] = (_Float16)hi.y;
            af[6] = (_Float16)hi.z; af[7] = (_Float16)hi.w;
            B16 bf;
            bf.u[0] = tab2[qa.x + (qa.y << 4)];
            bf.u[1] = tab2[qa.z + (qa.w << 4)];
            bf.u[2] = tab2[qc.x + (qc.y << 4)];
            bf.u[3] = tab2[qc.z + (qc.w << 4)];
            tacc = __builtin_amdgcn_mfma_f32_16x16x32_f16(af, bf.v, tacc, 0, 0, 0);
        }
        const float scg = g == 0 ? sc.x : g == 1 ? sc.y : g == 2 ? sc.z : sc.w;
        acc[0] += scg * tacc[0]; acc[1] += scg * tacc[1];
        acc[2] += scg * tacc[2]; acc[3] += scg * tacc[3];
    }
    float* op = out + n;
    #pragma unroll
    for (int r = 0; r < 4; ++r)
        atomicAdd(op + (size_t)(quad * 4 + r) * N_OUT, acc[r]);
}

extern "C" void kernel_launch(void* const* d_in, const int* in_sizes, int n_in,
                              void* d_out, int out_size, void* d_ws, size_t ws_size,
                              hipStream_t stream) {
    const float* x      = (const float*)d_in[0];
    const int*   qw     = (const int*)  d_in[1];
    const float* scales = (const float*)d_in[2];
    const float* tables = (const float*)d_in[3];
    float*       out    = (float*)d_out;

    const size_t ws_needed = (QP_WORDS + (size_t)NSL * OUT_ELEMS) * sizeof(uint32_t);
    dim3 block(256);

    if (ws_size >= ws_needed) {
        uint32_t* qp   = (uint32_t*)d_ws;
        float*    part = (float*)d_ws + PART_OFF;
        qpack<<<dim3(7168), block, 0, stream>>>((const int4*)qw, (uint4*)qp);
        flute_main<<<dim3(1792), block, 0, stream>>>(x, qp, scales, tables, part);
        flute_reduce<<<dim3(OUT_ELEMS / 4 / 256), block, 0, stream>>>(
            (const float4*)part, (float4*)out);
    } else {
        hipMemsetAsync(out, 0, (size_t)out_size * sizeof(float), stream);
        flute_atomic<<<dim3(1792), block, 0, stream>>>(x, qw, scales, tables, out);
    }
}

// Round 4
// 331.159 us; speedup vs baseline: 1.0950x; 1.0950x over previous
//
#include <hip/hip_runtime.h>
#include <stdint.h>

// FluteLinear: out[m,n] = sum_k x[m,k] * tables[qweight[n,k]] * scales[n, k/128]
// M=16, N=14336, K=4096, GROUP=128 (G=32). qweight = 235 MB int32.
//
// Round-6: round-3 retry (compile fix only). __builtin_nontemporal_load
// rejects HIP_vector_type int4 -> use clang ext_vector_type(4) int instead.
//
// Budget model (explains rounds 0-2): total = ~210 us fixed harness (896 MiB
// d_ws poison fill ~140 us + ~70 us of tiny reset memsets) + q-phase + ~3 us.
// The poison fill leaves L2+L3 (288 MiB) full of DIRTY lines; every cache-
// allocating q fetch victimizes one -> ~288 MiB forced writebacks convoyed
// with our 235 MB read = (235+288)/~5 TB/s ~= 105 us, exactly round-0's
// flute_main. Three different q access patterns (scattered, gload_lds bursts,
// pure-copy pack) all hit this same taxed floor -> pattern was never the
// limiter; the victimization tax is. Fix: nt loads don't allocate in L2/L3,
// so no victims, no writebacks - the dirty poison stays resident and is
// overwritten in-cache by the NEXT iteration's fill (same addresses).
//
// Predicted: total 318 -> ~255-270 us if nt no-allocates; ~318 (null) if nt
// is L1-only (then: q-phase is at its structural floor -> roofline or sc1
// probe next); >330 means nt broke line reuse -> revert.

#define K_DIM     4096
#define N_OUT     14336
#define G_CNT     32
#define KCHUNK    512
#define NKC       8
#define OUT_ELEMS (16 * 14336)

typedef _Float16 f16x8 __attribute__((ext_vector_type(8)));
typedef float    f32x4 __attribute__((ext_vector_type(4)));
typedef int      i32x4 __attribute__((ext_vector_type(4)));   // NT-loadable int4

union H2U { uint16_t u; _Float16 h; };
union B16 { uint32_t u[4]; f16x8 v; };

// 8 x i32x4 = one 128-k group of q codes for this lane (quad's 8 ints per
// 32-k step). NON-TEMPORAL: bypass cache allocation -> no dirty-poison
// victims from the 896 MiB harness fill.
#define LOADG(dst, base)                                                     \
    do {                                                                     \
        _Pragma("unroll")                                                    \
        for (int _s = 0; _s < 4; ++_s) {                                     \
            dst[2 * _s]     = __builtin_nontemporal_load(                    \
                                  (const i32x4*)((base) + _s * 32));         \
            dst[2 * _s + 1] = __builtin_nontemporal_load(                    \
                                  (const i32x4*)((base) + _s * 32 + 4));     \
        }                                                                    \
    } while (0)

__global__ __launch_bounds__(256, 3)
void flute_main(const float* __restrict__ x,
                const int*   __restrict__ qw,
                const float* __restrict__ scales,
                const float* __restrict__ tables,
                float*       __restrict__ ws,   // [8][16][14336] partials (or out in atomic mode)
                int          use_atomic) {
    // tab2[c0 | c1<<4] = packed (f16(tables[c0]), f16(tables[c1]))
    __shared__ uint32_t tab2[256];
    {
        H2U lo, hi;
        lo.h = (_Float16)tables[threadIdx.x & 15];
        hi.h = (_Float16)tables[threadIdx.x >> 4];
        tab2[threadIdx.x] = (uint32_t)lo.u | ((uint32_t)hi.u << 16);
    }
    __syncthreads();

    const int tid  = threadIdx.x;
    const int lane = tid & 63;
    const int wave = tid >> 6;
    const int b    = blockIdx.x;
    const int kc   = b & 7;                 // 4 waves share kc -> shared x slice stays hot
    const int nt   = (b >> 3) * 4 + wave;   // 0..895
    const int n0   = nt << 4;
    const int k0   = kc * KCHUNK;

    const int row  = lane & 15;             // m for A; n-offset for B; col for D
    const int quad = lane >> 4;             // k-subgroup quad*8..quad*8+7

    const int n = n0 + row;
    const int* qp = qw + (size_t)n * K_DIM + k0 + quad * 8;

    i32x4 q0[8], q1[8];
    LOADG(q0, qp);                          // group 0 in flight ASAP

    // ---- preload all x as 16 f16 A-fragments (k-loop then has q-only VMEM) ----
    f16x8 a[16];
    {
        const float* xp = x + row * K_DIM + k0 + quad * 8;
        #pragma unroll
        for (int s = 0; s < 16; ++s) {
            const float4 lo = *(const float4*)(xp + s * 32);
            const float4 hi = *(const float4*)(xp + s * 32 + 4);
            f16x8 af;
            af[0] = (_Float16)lo.x; af[1] = (_Float16)lo.y;
            af[2] = (_Float16)lo.z; af[3] = (_Float16)lo.w;
            af[4] = (_Float16)hi.x; af[5] = (_Float16)hi.y;
            af[6] = (_Float16)hi.z; af[7] = (_Float16)hi.w;
            a[s] = af;
        }
    }
    const float4 sc = *(const float4*)(scales + n * G_CNT + kc * 4);

    // one 128-k group: 4 MFMA steps fed by LDS pair-lookups (codes are 0..15 by
    // construction -> no masking; idx = c0 + (c1<<4) is one v_lshl_add_u32)
    auto dequant_group = [&](const i32x4* qb, const f16x8* af) {
        f32x4 accg = {0.f, 0.f, 0.f, 0.f};
        #pragma unroll
        for (int s = 0; s < 4; ++s) {
            const i32x4 qa = qb[2 * s];
            const i32x4 qc = qb[2 * s + 1];
            B16 bf;
            bf.u[0] = tab2[qa.x + (qa.y << 4)];
            bf.u[1] = tab2[qa.z + (qa.w << 4)];
            bf.u[2] = tab2[qc.x + (qc.y << 4)];
            bf.u[3] = tab2[qc.z + (qc.w << 4)];
            accg = __builtin_amdgcn_mfma_f32_16x16x32_f16(af[s], bf.v, accg, 0, 0, 0);
        }
        return accg;
    };

    // ---- 2-stage pipeline over the 4 scale groups ----
    f32x4 acc = {0.f, 0.f, 0.f, 0.f};
    f32x4 t;
    LOADG(q1, qp + 128);                    // group 1 in flight
    t = dequant_group(q0, a + 0);           // consume g0 (vmcnt(8): g1 stays out)
    acc[0] += sc.x * t[0]; acc[1] += sc.x * t[1]; acc[2] += sc.x * t[2]; acc[3] += sc.x * t[3];
    LOADG(q0, qp + 256);                    // group 2 in flight
    t = dequant_group(q1, a + 4);
    acc[0] += sc.y * t[0]; acc[1] += sc.y * t[1]; acc[2] += sc.y * t[2]; acc[3] += sc.y * t[3];
    LOADG(q1, qp + 384);                    // group 3 in flight
    t = dequant_group(q0, a + 8);
    acc[0] += sc.z * t[0]; acc[1] += sc.z * t[1]; acc[2] += sc.z * t[2]; acc[3] += sc.z * t[3];
    t = dequant_group(q1, a + 12);
    acc[0] += sc.w * t[0]; acc[1] += sc.w * t[1]; acc[2] += sc.w * t[2]; acc[3] += sc.w * t[3];

    // ---- D layout: col = lane&15 (= n-n0), rowD = quad*4 + r (= m) ----
    if (use_atomic) {
        float* op = ws + n;                 // ws == out here
        #pragma unroll
        for (int r = 0; r < 4; ++r) atomicAdd(op + (quad * 4 + r) * N_OUT, acc[r]);
    } else {
        float* op = ws + (size_t)kc * OUT_ELEMS + n;
        #pragma unroll
        for (int r = 0; r < 4; ++r) op[(size_t)(quad * 4 + r) * N_OUT] = acc[r];
    }
}

__global__ __launch_bounds__(256)
void flute_reduce(const float4* __restrict__ ws, float4* __restrict__ out) {
    const int i = blockIdx.x * 256 + threadIdx.x;   // 0..57343 (float4 index)
    float4 s = ws[i];
    #pragma unroll
    for (int kc = 1; kc < NKC; ++kc) {
        const float4 t = ws[(size_t)kc * (OUT_ELEMS / 4) + i];
        s.x += t.x; s.y += t.y; s.z += t.z; s.w += t.w;
    }
    out[i] = s;
}

extern "C" void kernel_launch(void* const* d_in, const int* in_sizes, int n_in,
                              void* d_out, int out_size, void* d_ws, size_t ws_size,
                              hipStream_t stream) {
    const float* x      = (const float*)d_in[0];
    const int*   qw     = (const int*)  d_in[1];
    const float* scales = (const float*)d_in[2];
    const float* tables = (const float*)d_in[3];
    float*       out    = (float*)d_out;

    const size_t ws_needed = (size_t)NKC * OUT_ELEMS * sizeof(float);  // 7.34 MB
    dim3 grid(1792), block(256);

    if (ws_size >= ws_needed) {
        float* ws = (float*)d_ws;
        flute_main<<<grid, block, 0, stream>>>(x, qw, scales, tables, ws, 0);
        flute_reduce<<<dim3(OUT_ELEMS / 4 / 256), block, 0, stream>>>(
            (const float4*)ws, (float4*)out);
    } else {
        // fallback: accumulate directly into out (needs zeroed out)
        (void)hipMemsetAsync(out, 0, (size_t)out_size * sizeof(float), stream);
        flute_main<<<grid, block, 0, stream>>>(x, qw, scales, tables, out, 1);
    }
}